// Round 5
// baseline (223.565 us; speedup 1.0000x reference)
//
#include <hip/hip_runtime.h>

#define TOKENS 16384
#define EMB 4096
#define NEXP 64
#define BT 32
#define BK 32
#define KSPLIT 2
#define KPER (EMB / KSPLIT)   // 2048
#define NCHUNK (KPER / BK)    // 64

// async global->LDS, 16B/lane; LDS dest = wave-uniform base + lane*16
__device__ __forceinline__ void gl_lds16(const float* g, void* lds) {
    __builtin_amdgcn_global_load_lds(
        (const __attribute__((address_space(1))) void*)g,
        (__attribute__((address_space(3))) void*)lds, 16, 0, 0);
}

// Kernel 1: partial GEMM. Block = 32 tokens x 64 experts x K-half.
// grid (512, KSPLIT) = 1024 blocks -> exactly 4 blocks/CU resident
// (LDS 24 KB/block, VGPR capped 128). Each SIMD hosts 4 waves from 4
// DIFFERENT blocks, so per-chunk barrier drains of one block overlap
// compute of the other three (R4 had 2 waves/SIMD, barrier-locked).
// Thread (tx,ty): experts 4tx..4tx+3, tokens 2ty..2ty+1.
// BOTH LDS tiles XOR-swizzled (R4 left X linear -> 16.8M bank-conflict
// cycles: row-stride 16 slots drops out of bank index mod 8, so all 4 X
// rows hit one bank-quad). Scheme: slot s of row r holds k-quad
// s ^ swz(r); swzX(r)=(r>>1)&7, swzW(r)=(r>>2)&7. Swizzle realized by
// pre-swizzling the GLOBAL source (global_load_lds writes linearly;
// XOR is an involution -> same permutation on read).
// Precision (R3/R4-validated): dual fp32 fma banks (even/odd kq) folded
// into fp64 every 32-k chunk; logit err ~1e-7 << top-2/3 gap.
__global__ __launch_bounds__(256, 4) void router_partial(
    const float* __restrict__ x, const float* __restrict__ W,
    float* __restrict__ ws)
{
    __shared__ float4 sX[2][BT][8];    // 8 KB
    __shared__ float4 sW[2][NEXP][8];  // 16 KB

    const int t  = threadIdx.x;
    const int l  = t & 63;        // lane
    const int wv = t >> 6;        // wave 0..3
    const int tx = t & 15;        // expert group
    const int ty = t >> 4;        // token pair 0..15
    const int t0 = blockIdx.x * BT;
    const int kb = blockIdx.y * KPER;

    // X stage: wave wv stages rows 8wv..8wv+7 (one 1024B instr);
    // lane l -> row 8wv+(l>>3), slot l&7 holds k-quad (l&7)^swzX(row),
    // swzX(8wv+(l>>3)) = (4wv+(l>>4))&7
    const float* gx;
    {
        const int r  = 8 * wv + (l >> 3);
        const int sw = (4 * wv + (l >> 4)) & 7;
        gx = x + (size_t)(t0 + r) * EMB + kb + 4 * ((l & 7) ^ sw);
    }
    // W stage: wave wv stages instrs p=0,1 -> rows 8q..8q+7, q=2wv+p;
    // swzW(8q+(l>>3)) = (2q+(l>>5))&7
    const float* gw0;
    const float* gw1;
    {
        int q = 2 * wv;
        int r = 8 * q + (l >> 3);
        int sw = (2 * q + (l >> 5)) & 7;
        gw0 = W + (size_t)r * EMB + kb + 4 * ((l & 7) ^ sw);
        q = 2 * wv + 1;
        r = 8 * q + (l >> 3);
        sw = (2 * q + (l >> 5)) & 7;
        gw1 = W + (size_t)r * EMB + kb + 4 * ((l & 7) ^ sw);
    }

    double acc64[2][4];
#pragma unroll
    for (int i = 0; i < 2; ++i)
#pragma unroll
        for (int j = 0; j < 4; ++j) acc64[i][j] = 0.0;

    // prologue: stage chunk 0 into buf 0
    gl_lds16(gx,  &sX[0][8 * wv][0]);
    gl_lds16(gw0, &sW[0][16 * wv][0]);
    gl_lds16(gw1, &sW[0][16 * wv + 8][0]);
    __syncthreads();

    for (int kc = 0; kc < NCHUNK; ++kc) {
        const int buf = kc & 1;
        if (kc + 1 < NCHUNK) {  // async prefetch next chunk -> other buffer
            const int ko = (kc + 1) * BK;
            gl_lds16(gx  + ko, &sX[buf ^ 1][8 * wv][0]);
            gl_lds16(gw0 + ko, &sW[buf ^ 1][16 * wv][0]);
            gl_lds16(gw1 + ko, &sW[buf ^ 1][16 * wv + 8][0]);
        }

        float a0[2][4], a1[2][4];
#pragma unroll
        for (int i = 0; i < 2; ++i)
#pragma unroll
            for (int j = 0; j < 4; ++j) { a0[i][j] = 0.f; a1[i][j] = 0.f; }

        const float4 (*X4)[8] = sX[buf];
        const float4 (*W4)[8] = sW[buf];
#pragma unroll 2
        for (int kq = 0; kq < 8; ++kq) {
            const int xs  = kq ^ (ty & 7);  // bank-quad = xs: 4 distinct/wave
            const int wsl = kq ^ (tx & 7);  // 16 addrs over 8 quads: 2-way
            float4 xq[2], wq[4];
            xq[0] = X4[2 * ty][xs];
            xq[1] = X4[2 * ty + 1][xs];
#pragma unroll
            for (int j = 0; j < 4; ++j) wq[j] = W4[4 * tx + j][wsl];
#pragma unroll
            for (int i = 0; i < 2; ++i)
#pragma unroll
                for (int j = 0; j < 4; ++j) {
                    float s = (kq & 1) ? a1[i][j] : a0[i][j];  // static after unroll
                    s = fmaf(xq[i].x, wq[j].x, s);
                    s = fmaf(xq[i].y, wq[j].y, s);
                    s = fmaf(xq[i].z, wq[j].z, s);
                    s = fmaf(xq[i].w, wq[j].w, s);
                    if (kq & 1) a1[i][j] = s; else a0[i][j] = s;
                }
        }
#pragma unroll
        for (int i = 0; i < 2; ++i)
#pragma unroll
            for (int j = 0; j < 4; ++j)
                acc64[i][j] += (double)a0[i][j] + (double)a1[i][j];

        __syncthreads();  // drains vmcnt(0): prefetched chunk landed
    }

    // fp32 partials: ws[(split*64 + e)*TOKENS + token], float2 over token pair
#pragma unroll
    for (int j = 0; j < 4; ++j) {
        float2 v;
        v.x = (float)acc64[0][j];
        v.y = (float)acc64[1][j];
        float* dst = ws + (size_t)(blockIdx.y * NEXP + 4 * tx + j) * TOKENS
                   + t0 + 2 * ty;
        *reinterpret_cast<float2*>(dst) = v;
    }
}

// Kernel 2: combine K-split partials + bias, top-2, softmax. 1 thread/token.
__global__ __launch_bounds__(256) void reduce_topk(
    const float* __restrict__ ws, const float* __restrict__ b,
    float* __restrict__ out)
{
    const int tok = blockIdx.x * 256 + threadIdx.x;
    float v1 = -3.4e38f, v2 = -3.4e38f;
    int i1 = 0, i2 = 0;
#pragma unroll 8
    for (int e = 0; e < NEXP; ++e) {
        float v = ws[(size_t)e * TOKENS + tok]
                + ws[(size_t)(NEXP + e) * TOKENS + tok] + b[e];
        if (v > v1) { v2 = v1; i2 = i1; v1 = v; i1 = e; }
        else if (v > v2) { v2 = v; i2 = e; }
    }
    float e2  = expf(v2 - v1);   // <= 1
    float inv = 1.0f / (1.0f + e2);
    out[2 * tok]     = (float)i1;
    out[2 * tok + 1] = (float)i2;
    out[2 * TOKENS + 2 * tok]     = inv;
    out[2 * TOKENS + 2 * tok + 1] = e2 * inv;
}

extern "C" void kernel_launch(void* const* d_in, const int* in_sizes, int n_in,
                              void* d_out, int out_size, void* d_ws, size_t ws_size,
                              hipStream_t stream) {
    const float* x = (const float*)d_in[0];
    const float* W = (const float*)d_in[1];
    const float* b = (const float*)d_in[2];
    float* out = (float*)d_out;
    float* ws  = (float*)d_ws;   // KSPLIT*NEXP*TOKENS*4 = 8.4 MB (fit proven R4)

    router_partial<<<dim3(TOKENS / BT, KSPLIT), dim3(256), 0, stream>>>(x, W, ws);
    reduce_topk<<<dim3(TOKENS / 256), dim3(256), 0, stream>>>(ws, b, out);
}